// Round 14
// baseline (26.571 us; speedup 1.0000x reference)
//
#include <hip/hip_runtime.h>
#include <stdint.h>

// qint embedding gather: out[t,:] = f32(w[x[t],:]) * scales[x[t]]
//
// R14: grid-stride + prefetch + nontemporal stores.
//   x:       [16384]        int32   token indices (= out_size/1024)
//   weights: [50257, 1024]  int32   (int8 values widened by harness)
//   scales:  [50257]        float32
//   out:     [16384, 1024]  float32 (bit-exact vs reference f32 multiply)
//
// 2048 blocks x 256 threads = 8192 waves = 256 CU x 32 waves -> exactly-full
// occupancy in one dispatch wave. Each block handles 8 tokens (grid-stride);
// x[] is prefetched one iteration ahead so the scales/row loads (which are
// mutually independent) issue immediately. Output is written with nt stores
// (write-once data; keep L2 for table rows re-read by duplicate tokens).
// Thread t covers dims [4t, 4t+4): dwordx4 load -> 4x cvt+mul -> dwordx4 store.

typedef float f32x4 __attribute__((ext_vector_type(4)));

__global__ __launch_bounds__(256) void qe_k(const int* __restrict__ x,
                                            const int* __restrict__ w,
                                            const float* __restrict__ scales,
                                            float* __restrict__ out,
                                            int n_tokens) {
    const int t = threadIdx.x;                       // 0..255

    // Weight-layout sniff hoisted: once per block (L2-broadcast, ~free).
    const int4 p = *reinterpret_cast<const int4*>(w);
    const bool wide =
        (p.x == (int)(int8_t)p.x) && (p.y == (int)(int8_t)p.y) &&
        (p.z == (int)(int8_t)p.z) && (p.w == (int)(int8_t)p.w);

    int token = blockIdx.x;
    int idx   = (token < n_tokens) ? x[token] : 0;   // prefetched index

    while (token < n_tokens) {
        const int next_token = token + gridDim.x;
        const int next_idx   = (next_token < n_tokens) ? x[next_token] : 0;

        const float s = scales[idx];                 // independent of row load
        f32x4 o;
        if (wide) {
            // int32 table: row 4096 B; thread t loads 16 B, coalesced.
            const int4 v = reinterpret_cast<const int4*>(w + (size_t)idx * 1024)[t];
            o.x = (float)v.x * s;
            o.y = (float)v.y * s;
            o.z = (float)v.z * s;
            o.w = (float)v.w * s;
        } else {
            // packed int8 table: row 1024 B; thread t loads 4 B, coalesced.
            const int r = reinterpret_cast<const int*>(
                reinterpret_cast<const int8_t*>(w) + (size_t)idx * 1024)[t];
            o.x = (float)(int8_t)(r)       * s;
            o.y = (float)(int8_t)(r >> 8)  * s;
            o.z = (float)(int8_t)(r >> 16) * s;
            o.w = (float)(int8_t)(r >> 24) * s;
        }

        // Write-once output: nontemporal dwordx4 store.
        __builtin_nontemporal_store(
            o, reinterpret_cast<f32x4*>(out + (size_t)token * 1024) + t);

        token = next_token;
        idx   = next_idx;
    }
}

extern "C" void kernel_launch(void* const* d_in, const int* in_sizes, int n_in,
                              void* d_out, int out_size, void* d_ws, size_t ws_size,
                              hipStream_t stream) {
    const int n_tokens = out_size / 1024;            // 16384
    if (n_tokens <= 0) return;

    // Bind inputs by element count (robust to ordering):
    // weights = largest; x = the one sized n_tokens; scales = remaining.
    int iw = 0;
    for (int i = 1; i < n_in; ++i)
        if (in_sizes[i] > in_sizes[iw]) iw = i;
    int ix = -1, is = -1;
    for (int i = 0; i < n_in; ++i) {
        if (i == iw) continue;
        if (in_sizes[i] == n_tokens && ix < 0) ix = i; else is = i;
    }
    if (ix < 0) ix = (iw == 0) ? 1 : 0;
    if (is < 0) is = 3 - ix - iw;

    const int blocks = (n_tokens < 2048) ? n_tokens : 2048;
    qe_k<<<blocks, 256, 0, stream>>>((const int*)d_in[ix], (const int*)d_in[iw],
                                     (const float*)d_in[is], (float*)d_out,
                                     n_tokens);
}